// Round 15
// baseline (306.674 us; speedup 1.0000x reference)
//
#include <hip/hip_runtime.h>
#include <hip/hip_bf16.h>

typedef __hip_bfloat16 bf16;
typedef short short8 __attribute__((ext_vector_type(8)));
typedef float f32x4 __attribute__((ext_vector_type(4)));
typedef unsigned uint2v __attribute__((ext_vector_type(2)));

__device__ __forceinline__ float b2f(bf16 v){ return __bfloat162float(v); }

__device__ __forceinline__ short f2bs(float f){
  union { __hip_bfloat16 b; short s; } u; u.b = __float2bfloat16(f); return u.s;
}
__device__ __forceinline__ float bs2f(short s){
  union { short s; __hip_bfloat16 b; } u; u.s = s; return __bfloat162float(u.b);
}
__device__ __forceinline__ unsigned pk2(float a, float b){
  return ((unsigned)(unsigned short)f2bs(a)) | (((unsigned)(unsigned short)f2bs(b)) << 16);
}

__device__ __forceinline__ float wred_sum(float v){
  #pragma unroll
  for (int o = 32; o > 0; o >>= 1) v += __shfl_xor(v, o, 64);
  return v;
}

// direct global->LDS DMA, 16B per lane. LDS dest = wave-uniform base + lane*16.
__device__ __forceinline__ void gload_lds16(const void* g, void* l){
  __builtin_amdgcn_global_load_lds((const __attribute__((address_space(1))) unsigned*)g,
                                   (__attribute__((address_space(3))) unsigned*)l, 16, 0, 0);
}

// XOR swizzles (involutions; key bits disjoint from modified bits).
// swzA: 256B-row buffers. 16-way -> 2-way conflict.
__device__ __forceinline__ unsigned swzA(unsigned a){ return a ^ (((a >> 8) & 7u) << 4); }
// swzB: 64B-row buffer (W2 chunk). 8-way -> 2-way conflict.
__device__ __forceinline__ unsigned swzB(unsigned a){ return a ^ (((a >> 7) & 3u) << 4); }

// ---------------------------------------------------------------------------
// modality helper (128 threads), v3 BATCHED: 4 bt per block. Each W element
// is loaded ONCE and feeds 4 independent FMA chains (one per bt) -> W re-read
// traffic /4 (78MB -> 19.6MB) and 4x FMA-per-load ILP. This is the session's
// proven redundant-load-elimination mechanism (proj r2 / attn r3 / probs r4),
// NOT a schedule reorder (r13's mistake).
// xs4 = [4][600] floats in LDS (broadcast reads, conflict-free).
// ---------------------------------------------------------------------------
template<int DIMN>
__device__ void modality4(const float* x, const float* W, const float* bia, const float* ph,
                          float* PURE, float* RNORM, int m, int bt0, float* xs4, float* red)
{
  int tid = threadIdx.x;
  #pragma unroll
  for (int j = 0; j < 4; j++)
    for (int i = tid; i < DIMN; i += 128) xs4[j*600 + i] = x[(size_t)(bt0+j)*DIMN + i];
  __syncthreads();
  float acc0 = 0.f, acc1 = 0.f, acc2 = 0.f, acc3 = 0.f;
  for (int k = 0; k < DIMN; k++){
    float w = W[k*128 + tid];
    acc0 = fmaf(xs4[        k], w, acc0);
    acc1 = fmaf(xs4[ 600 + k], w, acc1);
    acc2 = fmaf(xs4[1200 + k], w, acc2);
    acc3 = fmaf(xs4[1800 + k], w, acc3);
  }
  float bv = bia[tid];
  float p  = ph[tid];
  float cp = cosf(p), sp = sinf(p);
  float rep[4];
  rep[0] = fmaxf(acc0 + bv, 0.f);
  rep[1] = fmaxf(acc1 + bv, 0.f);
  rep[2] = fmaxf(acc2 + bv, 0.f);
  rep[3] = fmaxf(acc3 + bv, 0.f);
  int wid = tid >> 6, lane = tid & 63;
  #pragma unroll
  for (int j = 0; j < 4; j++){
    float s = wred_sum(rep[j]*rep[j]);
    if (lane == 0) red[wid] = s;
    __syncthreads();
    float nrm = sqrtf(red[0] + red[1]);
    float amp = rep[j] / fmaxf(nrm, 1e-12f);
    int bt = bt0 + j;
    PURE[bt*768 + m*128 + tid]       = amp * cp;
    PURE[bt*768 + (3+m)*128 + tid]   = amp * sp;
    if (tid == 0) RNORM[bt*4 + m] = nrm;
    __syncthreads();
  }
}

// ---------------------------------------------------------------------------
// Kernel 0 MERGED PREP (LDS-tiled 32x32 transposes; modality x4; lang; meas).
// Grid 705: [0,384) transpose, [384,576) modality (m=idx>>6, bt0=(idx&63)*4),
// 576 lang, [577,705) meas.
// ---------------------------------------------------------------------------
__global__ void prep_kernel(
    const float* __restrict__ Wqkv, const float* __restrict__ Wo,
    const float* __restrict__ W1, const float* __restrict__ W2,
    short* __restrict__ WqkvT, short* __restrict__ WoT,
    short* __restrict__ W1T, short* __restrict__ W2T,
    const float* xt, const float* xv, const float* xa,
    const float* Wpt, const float* bpt, const float* Wpv, const float* bpv,
    const float* Wpa, const float* bpa,
    const float* pht, const float* phv, const float* pha,
    float* PURE, float* RNORM,
    const float* l1, const float* l2,
    const float* Wl1, const float* bl1, const float* Wl2, const float* bl2,
    float* LANGB,
    const float* mr, const float* mi, float* VMEAS, short* VMEASB)
{
  __shared__ float xs4[2400];          // modality staging [4][600]; lang reuses
  __shared__ float red[4];
  __shared__ float tile[32][33];
  int b = blockIdx.x, tid = threadIdx.x;
  float* xs   = xs4;                   // lang: l1 staging [600]
  float* xs2a = xs4 + 600;             // lang: l2 staging [300]

  if (b < 384){
    int l = b / 192, bb = b - l*192;
    const float* in; short* out; int K, N, kt, nt_;
    bool isW2 = false;
    if (bb < 48)      { in = Wqkv; out = WqkvT; K = 128; N = 384; kt = bb & 3;  nt_ = bb >> 2; }
    else if (bb < 64) { int t = bb-48;  in = Wo; out = WoT; K = 128; N = 128; kt = t & 3;  nt_ = t >> 2; }
    else if (bb < 128){ int t = bb-64;  in = W1; out = W1T; K = 128; N = 512; kt = t & 3;  nt_ = t >> 2; }
    else              { int t = bb-128; in = W2; out = W2T; K = 512; N = 128; kt = t & 15; nt_ = t >> 4; isW2 = true; }
    int base = l * K * N;
    int kk0 = kt*32, nn0 = nt_*32;
    int r0 = tid >> 5, c = tid & 31;
    #pragma unroll
    for (int i = 0; i < 8; i++){
      int r = i*4 + r0;
      tile[r][c] = in[base + (kk0 + r)*N + nn0 + c];
    }
    __syncthreads();
    #pragma unroll
    for (int i = 0; i < 8; i++){
      int rr = i*4 + r0;
      float v = tile[c][rr];
      int oi;
      if (!isW2) oi = (nn0 + rr)*K + kk0 + c;
      else       oi = kt*4096 + (nn0 + rr)*32 + c;
      out[base + oi] = f2bs(v);
    }
    return;
  }
  if (b < 576){
    int idx = b - 384;                 // 0..191
    int m = idx >> 6, g = idx & 63;
    int bt0 = g*4;
    if (m == 0)      modality4<600>(xt, Wpt, bpt, pht, PURE, RNORM, 0, bt0, xs4, red);
    else if (m == 1) modality4<342>(xv, Wpv, bpv, phv, PURE, RNORM, 1, bt0, xs4, red);
    else             modality4<300>(xa, Wpa, bpa, pha, PURE, RNORM, 2, bt0, xs4, red);
    return;
  }
  if (b >= 577){
    int k = b - 577;
    float a = mr[k*128 + tid], bb2 = mi[k*128 + tid];
    float ws = wred_sum(a*a + bb2*bb2);
    int wid = tid >> 6, lane = tid & 63;
    if (lane == 0) red[wid] = ws;
    __syncthreads();
    float inv = 1.f / fmaxf(sqrtf(red[0] + red[1]), 1e-12f);
    float vr = a * inv, vi = bb2 * inv;
    int i = k*128 + tid;
    VMEAS[i]          = vr;
    VMEAS[16384 + i]  = vi;
    VMEASB[i]         = f2bs(vr);
    VMEASB[16384 + i] = f2bs(vi);
    VMEASB[32768 + i] = f2bs(-vi);
    return;
  }
  // ---- lang path (single block, b == 576) ----
  for (int i = tid; i < 300; i += 128){ xs[i] = l1[i]; xs2a[i] = l2[i]; }
  __syncthreads();
  float p10=0,p11=0,p12=0,p13=0, p20=0,p21=0,p22=0,p23=0;
  for (int k = 0; k < 300; k += 4){
    p10 = fmaf(xs[k],    Wl1[(k  )*128+tid], p10);
    p11 = fmaf(xs[k+1],  Wl1[(k+1)*128+tid], p11);
    p12 = fmaf(xs[k+2],  Wl1[(k+2)*128+tid], p12);
    p13 = fmaf(xs[k+3],  Wl1[(k+3)*128+tid], p13);
    p20 = fmaf(xs2a[k],  Wl2[(k  )*128+tid], p20);
    p21 = fmaf(xs2a[k+1],Wl2[(k+1)*128+tid], p21);
    p22 = fmaf(xs2a[k+2],Wl2[(k+2)*128+tid], p22);
    p23 = fmaf(xs2a[k+3],Wl2[(k+3)*128+tid], p23);
  }
  float a1 = bl1[tid] + ((p10+p11)+(p12+p13));
  float a2 = bl2[tid] + ((p20+p21)+(p22+p23));
  a1 = fmaxf(a1, 0.f); a2 = fmaxf(a2, 0.f);
  int wid = tid >> 6, lane = tid & 63;
  float s1 = wred_sum(a1*a1), s2 = wred_sum(a2*a2);
  if (lane == 0){ red[wid] = s1; red[2+wid] = s2; }
  __syncthreads();
  float n1 = sqrtf(red[0] + red[1]);
  float n2 = sqrtf(red[2] + red[3]);
  float lamp1 = a1 / fmaxf(n1, 1e-12f);
  float lamp2 = a2 / fmaxf(n2, 1e-12f);
  float ph = pht[tid];
  float c = cosf(ph), s = sinf(ph);
  const float s2c = 0.70710678118654752f;
  float h1r = (lamp1*c + lamp1*s)*s2c, h1i = (lamp1*c - lamp1*s)*s2c;
  float h2r = (lamp2*c + lamp2*s)*s2c, h2i = (lamp2*c - lamp2*s)*s2c;
  float er = h1r*h2r - h1i*h2i;
  float ei = h1r*h2i + h1i*h2r;
  __syncthreads();
  float se = wred_sum(er*er + ei*ei);
  if (lane == 0) red[wid] = se;
  __syncthreads();
  float en = fmaxf(sqrtf(red[0] + red[1]), 1e-12f);
  LANGB[tid]       = er / en;
  LANGB[128 + tid] = ei / en;
  if (tid == 0) LANGB[256] = n1;
}

// ---------------------------------------------------------------------------
// Kernel 3: weighted sum of rank-1 density matrices -> Xb (bf16).
// grid 2048: each block computes a 2048-elem quarter (32 waves/CU).
// bt = b & 255 keeps XCD alignment.
// ---------------------------------------------------------------------------
__global__ __launch_bounds__(256) void rho_kernel(const float* PURE, const float* RNORM,
                                                  const float* LANGB, short* Xb)
{
  __shared__ float rv[4][128], iv[4][128], wsm[4];
  int bt = blockIdx.x & 255, quarter = blockIdx.x >> 8;   // 0..7
  int tid = threadIdx.x;
  for (int i = tid; i < 1024; i += 256){
    int d = i & 127;
    if (i < 768){ int m = i >> 7; float v = PURE[bt*768 + i];
                  if (m < 3) rv[m][d] = v; else iv[m-3][d] = v; }
    else if (i < 896) rv[3][d] = LANGB[d];
    else              iv[3][d] = LANGB[128 + d];
  }
  if (tid == 0){
    float n0 = RNORM[bt*4+0], n1 = RNORM[bt*4+1], n2 = RNORM[bt*4+2], n3 = LANGB[256];
    float mx = fmaxf(fmaxf(n0, n1), fmaxf(n2, n3));
    float e0 = __expf(n0-mx), e1 = __expf(n1-mx), e2 = __expf(n2-mx), e3 = __expf(n3-mx);
    float inv = 1.f / (e0+e1+e2+e3);
    wsm[0]=e0*inv; wsm[1]=e1*inv; wsm[2]=e2*inv; wsm[3]=e3*inv;
  }
  __syncthreads();
  float w0 = wsm[0], w1 = wsm[1], w2 = wsm[2], w3 = wsm[3];
  int lo = quarter*2048, hi = lo + 2048;
  for (int idx = lo + tid; idx < hi; idx += 256){
    int d = idx >> 7, e = idx & 127;
    float rr = 0.f, ri = 0.f;
    {
      float rd=rv[0][d], re=rv[0][e], id=iv[0][d], ie=iv[0][e];
      rr = fmaf(w0, rd*re + id*ie, rr); ri = fmaf(w0, id*re - rd*ie, ri);
    }{
      float rd=rv[1][d], re=rv[1][e], id=iv[1][d], ie=iv[1][e];
      rr = fmaf(w1, rd*re + id*ie, rr); ri = fmaf(w1, id*re - rd*ie, ri);
    }{
      float rd=rv[2][d], re=rv[2][e], id=iv[2][d], ie=iv[2][e];
      rr = fmaf(w2, rd*re + id*ie, rr); ri = fmaf(w2, id*re - rd*ie, ri);
    }{
      float rd=rv[3][d], re=rv[3][e], id=iv[3][d], ie=iv[3][e];
      rr = fmaf(w3, rd*re + id*ie, rr); ri = fmaf(w3, id*re - rd*ie, ri);
    }
    Xb[(size_t)bt*16384 + idx]        = f2bs(rr);
    Xb[(size_t)(256+bt)*16384 + idx]  = f2bs(ri);
  }
}

// ---------------------------------------------------------------------------
// Kernel 4a: fused MHA per (n, head). grid (512,4), block 256.  [r8 best]
// v5 swapped QK^T softmax + packed P stores. LDS 43.5KB, 3 blocks/CU.
// ---------------------------------------------------------------------------
__global__ __launch_bounds__(256) void attn_kernel(const short* __restrict__ Xb,
    const short* __restrict__ WqkvT, const float* __restrict__ bqkv,
    bf16* __restrict__ ATTO)
{
  __shared__ __align__(16) char lds_raw[43520];
  short* Vt = (short*)(lds_raw);           // [32][136]
  short* Qs = (short*)(lds_raw + 8704);    // [128][40]
  short* Ks = (short*)(lds_raw + 18944);   // [128][40]
  short* Ps = (short*)(lds_raw + 8704);    // [128][136] row-major P[q][k]

  const int n = blockIdx.x, h = blockIdx.y;
  const int tid = threadIdx.x;
  const int wid = tid >> 6, lane = tid & 63;
  const int l15 = lane & 15, quad = lane >> 4;
  const int wb = __builtin_amdgcn_readfirstlane(wid);
  const short* xn = Xb + (size_t)n*16384;
  const char* Wbase = (const char*)WqkvT;

  short8 afr[2][4];
  #pragma unroll
  for (int mi = 0; mi < 2; mi++)
    #pragma unroll
    for (int ks = 0; ks < 4; ks++){
      int row = (wid*2 + mi)*16 + l15;
      afr[mi][ks] = *(const short8*)(xn + row*128 + ks*32 + quad*8);
    }
  #pragma unroll
  for (int j = 0; j < 6; j++){
    int seg = wb*6 + j;                 // 0..23
    int slab = seg >> 3;                // 0=q,1=k,2=v
    unsigned off = (unsigned)((seg & 7)*1024);
    unsigned gbase = (unsigned)((slab*128 + h*32)*256);
    gload_lds16(Wbase + gbase + swzA(off + (unsigned)(lane*16)),
                lds_raw + seg*1024);
  }
  __syncthreads();

  f32x4 acc[2][6];
  #pragma unroll
  for (int mi = 0; mi < 2; mi++)
    #pragma unroll
    for (int nt = 0; nt < 6; nt++){
      f32x4 z = {0.f, 0.f, 0.f, 0.f}; acc[mi][nt] = z;
    }

  #pragma unroll
  for (int ks = 0; ks < 4; ks++){
    #pragma unroll
    for (int nt = 0; nt < 6; nt++){
      int slab = nt >> 1;
      int col = (nt & 1)*16 + l15;
      unsigned a = (unsigned)(col*256 + ks*64 + quad*16);
      short8 bfr = *(const short8*)(lds_raw + slab*8192 + swzA(a));
      #pragma unroll
      for (int mi = 0; mi < 2; mi++)
        acc[mi][nt] = __builtin_amdgcn_mfma_f32_16x16x32_bf16(afr[mi][ks], bfr, acc[mi][nt], 0, 0, 0);
    }
  }
  __syncthreads();

  #pragma unroll
  for (int nt = 0; nt < 6; nt++){
    int sec = nt >> 1;
    int cl = (nt & 1)*16 + l15;
    float bias = bqkv[sec*128 + h*32 + cl];
    #pragma unroll
    for (int mi = 0; mi < 2; mi++){
      int rowb = (wid*2 + mi)*16 + quad*4;
      #pragma unroll
      for (int r = 0; r < 4; r++){
        float v = acc[mi][nt][r] + bias;
        int row = rowb + r;
        if (sec == 0)      Qs[row*40 + cl] = f2bs(v * 0.17677669529663687f);
        else if (sec == 1) Ks[row*40 + cl] = f2bs(v);
        else               Vt[cl*136 + row] = f2bs(v);
      }
    }
  }
  __syncthreads();

  // ---- QK^T SWAPPED: s2[kt][qt] = S^T tile; lane holds S[q][k-slice] ----
  f32x4 s2[8][2];
  {
    short8 qf[2];
    #pragma unroll
    for (int qt = 0; qt < 2; qt++){
      int row = (wid*2 + qt)*16 + l15;
      qf[qt] = *(const short8*)(Qs + row*40 + quad*8);
    }
    #pragma unroll
    for (int kt = 0; kt < 8; kt++){
      int kr = kt*16 + l15;
      short8 kf = *(const short8*)(Ks + kr*40 + quad*8);
      #pragma unroll
      for (int qt = 0; qt < 2; qt++){
        f32x4 z = {0.f, 0.f, 0.f, 0.f};
        s2[kt][qt] = __builtin_amdgcn_mfma_f32_16x16x32_bf16(kf, qf[qt], z, 0, 0, 0);
      }
    }
  }

  // ---- softmax over k: per qt, in-lane 32-value reduce + 2 cross-quad shfls ----
  #pragma unroll
  for (int qt = 0; qt < 2; qt++){
    float mx = -1e30f;
    #pragma unroll
    for (int kt = 0; kt < 8; kt++)
      #pragma unroll
      for (int r = 0; r < 4; r++) mx = fmaxf(mx, s2[kt][qt][r]);
    mx = fmaxf(mx, __shfl_xor(mx, 16, 64));
    mx = fmaxf(mx, __shfl_xor(mx, 32, 64));
    float sum = 0.f;
    #pragma unroll
    for (int kt = 0; kt < 8; kt++)
      #pragma unroll
      for (int r = 0; r < 4; r++){
        float p = __expf(s2[kt][qt][r] - mx);
        s2[kt][qt][r] = p; sum += p;
      }
    sum += __shfl_xor(sum, 16, 64);
    sum += __shfl_xor(sum, 32, 64);
    float inv = 1.f / sum;
    #pragma unroll
    for (int kt = 0; kt < 8; kt++)
      #pragma unroll
      for (int r = 0; r < 4; r++) s2[kt][qt][r] *= inv;
  }
  __syncthreads();   // Qs/Ks reads done -> Ps may overlay

  // ---- packed P stores: 4 consecutive k per lane -> one b64 write ----
  #pragma unroll
  for (int kt = 0; kt < 8; kt++){
    #pragma unroll
    for (int qt = 0; qt < 2; qt++){
      int q  = (wid*2 + qt)*16 + l15;
      int k0 = kt*16 + quad*4;
      uint2v v;
      v.x = pk2(s2[kt][qt][0], s2[kt][qt][1]);
      v.y = pk2(s2[kt][qt][2], s2[kt][qt][3]);
      *(uint2v*)((char*)Ps + (unsigned)(q*272 + k0*2)) = v;
    }
  }
  __syncthreads();

  f32x4 o_[2][2];
  #pragma unroll
  for (int mi = 0; mi < 2; mi++)
    #pragma unroll
    for (int n2 = 0; n2 < 2; n2++){
      f32x4 z = {0.f, 0.f, 0.f, 0.f}; o_[mi][n2] = z;
    }
  #pragma unroll
  for (int ks = 0; ks < 4; ks++){
    short8 pf[2];
    #pragma unroll
    for (int mi = 0; mi < 2; mi++){
      int row = (wid*2 + mi)*16 + l15;
      pf[mi] = *(const short8*)(Ps + row*136 + ks*32 + quad*8);
    }
    #pragma unroll
    for (int n2 = 0; n2 < 2; n2++){
      short8 vf = *(const short8*)(Vt + (n2*16 + l15)*136 + ks*32 + quad*8);
      #pragma unroll
      for (int mi = 0; mi < 2; mi++)
        o_[mi][n2] = __builtin_amdgcn_mfma_f32_16x16x32_bf16(pf[mi], vf, o_[mi][n2], 0, 0, 0);
    }
  }
  bf16* on = ATTO + (size_t)n*16384;
  #pragma unroll
  for (int mi = 0; mi < 2; mi++){
    int rowb = (wid*2 + mi)*16 + quad*4;
    #pragma unroll
    for (int n2 = 0; n2 < 2; n2++){
      int col = h*32 + n2*16 + l15;
      #pragma unroll
      for (int r = 0; r < 4; r++)
        on[(rowb + r)*128 + col] = __float2bfloat16(o_[mi][n2][r]);
    }
  }
}

// ---------------------------------------------------------------------------
// Kernel 4bc FUSED: grid 512, block 256, 4 waves x 32 rows.
// v7 single-barrier chunk loop: per chunk { STAGE(c+1, other-buf);
// compute(c); vmcnt(0); barrier }.
// ---------------------------------------------------------------------------
__global__ __launch_bounds__(256, 2) void proj_ffn_kernel(const bf16* __restrict__ SRC,
    short* __restrict__ Xb, const short* __restrict__ WoT,
    const float* __restrict__ bo, const float* __restrict__ g1v,
    const float* __restrict__ bb1,
    const short* __restrict__ W1T, const float* __restrict__ bf1,
    const short* __restrict__ W2C, const float* __restrict__ bf2,
    const float* __restrict__ g2v, const float* __restrict__ bb2)
{
  __shared__ __align__(16) char lds_raw[65536];
  __shared__ float bf1L[512];
  const int n = blockIdx.x, tid = threadIdx.x;
  const int wid = tid >> 6, lane = tid & 63;
  const int l15 = lane & 15, quad = lane >> 4;
  const int wb = __builtin_amdgcn_readfirstlane(wid);
  const short* an = (const short*)SRC + (size_t)n*16384;
  short* xn = Xb + (size_t)n*16384;
  char* XsB = lds_raw + 32768;
  short* Hs = (short*)(lds_raw + 32768);

  // ---- t0: A-fragments (ATTO) to regs; stage WoT + residual(Xs); bf1->LDS ----
  short8 af[2][4];
  #pragma unroll
  for (int mi = 0; mi < 2; mi++)
    #pragma unroll
    for (int ks = 0; ks < 4; ks++){
      int row = wid*32 + mi*16 + l15;
      af[mi][ks] = *(const short8*)(an + row*128 + ks*32 + quad*8);
    }
  #pragma unroll
  for (int j = 0; j < 8; j++){
    unsigned L = (unsigned)(j*4096 + wb*1024 + lane*16);
    gload_lds16((const char*)WoT + swzA(L), lds_raw + (j*4096 + wb*1024));
    gload_lds16((const char*)xn  + swzA(L), XsB + (j*4096 + wb*1024));
  }
  for (int i = tid; i < 512; i += 256) bf1L[i] = bf1[i];
  float bov[8], g1a[8], b1a[8];
  #pragma unroll
  for (int nt = 0; nt < 8; nt++){
    int col = nt*16 + l15;
    bov[nt] = bo[col]; g1a[nt] = g1v[col]; b1a[nt] = bb1[col];
  }
  __syncthreads();   // WoT + Xs staged, bf1L visible

  // ---- Wo projection from LDS weights ----
  f32x4 Y[2][8];
  #pragma unroll
  for (int mi = 0; mi < 2; mi++)
    #pragma unroll
    for (int nt = 0; nt < 8; nt++){ f32x4 z = {0.f,0.f,0.f,0.f}; Y[mi][nt] = z; }
  #pragma unroll
  for (int ks = 0; ks < 4; ks++){
    #pragma unroll
    for (int nt = 0; nt < 8; nt++){
      unsigned a = (unsigned)((nt*16 + l15)*256 + ks*64 + quad*16);
      short8 bh = *(const short8*)(lds_raw + swzA(a));
      #pragma unroll
      for (int mi = 0; mi < 2; mi++)
        Y[mi][nt] = __builtin_amdgcn_mfma_f32_16x16x32_bf16(af[mi][ks], bh, Y[mi][nt], 0, 0, 0);
    }
  }
  __syncthreads();   // WoT region free for chunk buffers

  // ---- issue stage of FFN chunk 0 into buf0 ----
  #pragma unroll
  for (int j = 0; j < 2; j++){
    unsigned L = (unsigned)(j*4096 + wb*1024 + lane*16);
    gload_lds16((const char*)W1T + swzA(L), lds_raw + (j*4096 + wb*1024));
    gload_lds16((const char*)W2C + swzB(L), lds_raw + (8192 + j*4096 + wb*1024));
  }

  // ---- residual + LN1 (residual from Xs; output -> Xs bounce + packed regs) ----
  unsigned yv1p[2][4][4];
  #pragma unroll
  for (int mi = 0; mi < 2; mi++){
    #pragma unroll
    for (int r = 0; r < 4; r++){
      int row = wid*32 + mi*16 + quad*4 + r;
      float yv[8]; float S = 0.f, Q = 0.f;
      #pragma unroll
      for (int nt = 0; nt < 8; nt++){
        int col = nt*16 + l15;
        float res = bs2f(*(const short*)(XsB + swzA((unsigned)(row*256 + col*2))));
        float y = Y[mi][nt][r] + bov[nt] + res;
        yv[nt] = y; S += y; Q += y*y;
      }
      #pragma unroll
      for (int o = 1; o < 16; o <<= 1){ S += __shfl_xor(S, o, 64); Q += __shfl_xor(Q, o, 64); }
      float m = S * (1.f/128.f);
      float var = Q * (1.f/128.f) - m*m;
      float inv = rsqrtf(var + 1e-5f);
      #pragma unroll
      for (int nt = 0; nt < 8; nt++){
        int col = nt*16 + l15;
        short ob = f2bs((yv[nt] - m) * inv * g1a[nt] + b1a[nt]);
        *(short*)(XsB + swzA((unsigned)(row*256 + col*2))) = ob;
        unsigned u = (unsigned)(unsigned short)ob;
        if ((nt & 1) == 0) yv1p[mi][r][nt>>1] = u;
        else               yv1p[mi][r][nt>>1] |= (u << 16);
      }
    }
  }

  // ---- A-fragments of LN1 output (wave-private rows, via Xs bounce) ----
  short8 af2[2][4];
  #pragma unroll
  for (int mi = 0; mi < 2; mi++)
    #pragma unroll
    for (int ks = 0; ks < 4; ks++){
      int row = wid*32 + mi*16 + l15;
      unsigned a = (unsigned)(row*256 + ks*64 + quad*16);
      af2[mi][ks] = *(const short8*)(XsB + swzA(a));
    }
  __syncthreads();   // chunk0 staged(+drained) + all waves past Xs reads (Hs overlays)

  // ---- FFN: 16 chunks, double-buffered, ONE barrier per chunk ----
  f32x4 Y2[2][8];
  #pragma unroll
  for (int mi = 0; mi < 2; mi++)
    #pragma unroll
    for (int nt = 0; nt < 8; nt++){ f32x4 z = {0.f,0.f,0.f,0.f}; Y2[mi][nt] = z; }

  for (int c = 0; c < 16; c++){
    const int cb = c & 1;
    if (c < 15){
      const int nb = cb ^ 1;
      #pragma unroll
      for (int j = 0; j < 2; j++){
        unsigned L = (unsigned)(j*4096 + wb*1024 + lane*16);
        gload_lds16((const char*)W1T + (unsigned)((c+1)*8192) + swzA(L),
                    lds_raw + (nb*16384 + j*4096 + wb*1024));
        gload_lds16((const char*)W2C + (unsigned)((c+1)*8192) + swzB(L),
                    lds_raw + (nb*16384 + 8192 + j*4096 + wb*1024));
      }
    }
    const char* bW1 = lds_raw + cb*16384;
    const char* bW2 = lds_raw + cb*16384 + 8192;

    f32x4 Hc[2][2];
    #pragma unroll
    for (int mi = 0; mi < 2; mi++)
      #pragma unroll
      for (int nt2 = 0; nt2 < 2; nt2++){ f32x4 z = {0.f,0.f,0.f,0.f}; Hc[mi][nt2] = z; }
    #pragma unroll
    for (int ks = 0; ks < 4; ks++){
      #pragma unroll
      for (int nt2 = 0; nt2 < 2; nt2++){
        unsigned a = (unsigned)((nt2*16 + l15)*256 + ks*64 + quad*16);
        short8 bh = *(const short8*)(bW1 + swzA(a));
        #pragma unroll
        for (int mi = 0; mi < 2; mi++)
          Hc[mi][nt2] = __builtin_amdgcn_mfma_f32_16x16x32_bf16(af2[mi][ks], bh, Hc[mi][nt2], 0, 0, 0);
      }
    }
    float b1v0 = bf1L[c*32 + l15];
    float b1v1 = bf1L[c*32 + 16 + l15];
    #pragma unroll
    for (int nt2 = 0; nt2 < 2; nt2++){
      int col = nt2*16 + l15;
      float b1v = nt2 ? b1v1 : b1v0;
      #pragma unroll
      for (int mi = 0; mi < 2; mi++){
        int rowb = wid*32 + mi*16 + quad*4;
        #pragma unroll
        for (int r = 0; r < 4; r++)
          Hs[(rowb + r)*40 + col] = f2bs(fmaxf(Hc[mi][nt2][r] + b1v, 0.f));
      }
    }
    short8 ph[2];
    #pragma unroll
    for (int mi = 0; mi < 2; mi++){
      int row = wid*32 + mi*16 + l15;
      ph[mi] = *(const short8*)(Hs + row*40 + quad*8);
    }
    #pragma unroll
    for (int nt = 0; nt < 8; nt++){
      unsigned a = (unsigned)((nt*16 + l15)*64 + quad*16);
      short8 bh = *(const short8*)(bW2 + swzB(a));
      #pragma unroll
      for (int mi = 0; mi < 2; mi++)
        Y2[mi][nt] = __builtin_amdgcn_mfma_f32_16x16x32_bf16(ph[mi], bh, Y2[mi][nt], 0, 0, 0);
    }
    if (c < 15){
      asm volatile("s_waitcnt vmcnt(0)" ::: "memory");  // chunk c+1 landed
      __builtin_amdgcn_s_barrier();                     // + all reads of cb done
    }
  }

  // ---- residual (packed regs) + LN2 -> xn ----
  {
    float b2v[8], gv[8], bbv[8];
    #pragma unroll
    for (int nt = 0; nt < 8; nt++){
      int col = nt*16 + l15;
      b2v[nt] = bf2[col]; gv[nt] = g2v[col]; bbv[nt] = bb2[col];
    }
    #pragma unroll
    for (int mi = 0; mi < 2; mi++){
      #pragma unroll
      for (int r = 0; r < 4; r++){
        int row = wid*32 + mi*16 + quad*4 + r;
        float yv[8]; float S = 0.f, Q = 0.f;
        #pragma unroll
        for (int nt = 0; nt < 8; nt++){
          unsigned u = yv1p[mi][r][nt>>1];
          short rs = (short)((nt & 1) ? (u >> 16) : (u & 0xffffu));
          float y = Y2[mi][nt][r] + b2v[nt] + bs2f(rs);
          yv[nt] = y; S += y; Q += y*y;
        }
        #pragma unroll
        for (int o = 1; o < 16; o <<= 1){ S += __shfl_xor(S, o, 64); Q += __shfl_xor(Q, o, 64); }
        float m = S * (1.f/128.f);
        float var = Q * (1.f/128.f) - m*m;
        float inv = rsqrtf(var + 1e-5f);
        #pragma unroll
        for (int nt = 0; nt < 8; nt++){
          int col = nt*16 + l15;
          xn[row*128 + col] = f2bs((yv[nt] - m) * inv * gv[nt] + bbv[nt]);
        }
      }
    }
  }
}

// ---------------------------------------------------------------------------
// Kernel 5: probs + head FUSED. grid 256 (bt), block 512 (8 waves).
// v4 single-barrier chunk loop.
// ---------------------------------------------------------------------------
__global__ __launch_bounds__(512) void probs_head_kernel(const short* __restrict__ Xb,
    const float* __restrict__ VMEAS, const short* __restrict__ VMEASB,
    const float* __restrict__ W1, const float* __restrict__ b1,
    const float* __restrict__ W2, const float* __restrict__ b2,
    float* __restrict__ out)
{
  __shared__ __align__(16) char lds_raw[24576];   // dbuf[2] x {vr,vi,nvi} 4KB each
  __shared__ float sp[128];
  __shared__ float hsh[64];
  __shared__ float lg[7];
  __shared__ float mred[2];
  const int bt = blockIdx.x, tid = threadIdx.x;
  const int wid = tid >> 6, lane = tid & 63;
  const int l15 = lane & 15, quad = lane >> 4;
  const int wb = __builtin_amdgcn_readfirstlane(wid);
  const int zh = wb >> 2;          // z-half (0: rows 0-63, 1: rows 64-127)
  const int zq = wb & 3;           // 16-row quarter within the half
  const short* R = Xb + (size_t)bt*16384;
  const short* I = Xb + (size_t)(256+bt)*16384;

  if (tid < 128) sp[tid] = 0.f;

  // ---- A-fragments (single z-half per wave) ----
  const int drow = zh*64 + zq*16 + l15;
  short8 aR[4], aI[4];
  #pragma unroll
  for (int ks = 0; ks < 4; ks++){
    aR[ks] = *(const short8*)(R + drow*128 + ks*32 + quad*8);
    aI[ks] = *(const short8*)(I + drow*128 + ks*32 + quad*8);
  }

  // stage chunk nt (12KB = 12 x 1KB segs, 2 per wave for waves 0..5)
  #define STAGE_NT(nt_, buf_)                                                  \
    { _Pragma("unroll")                                                        \
      for (int j = 0; j < 2; j++){                                             \
        int seg = wb*2 + j;            /* 0..15, use 0..11 */                  \
        if (seg < 12){                                                         \
          int s = seg >> 2;            /* slab 0..2 */                         \
          unsigned off = (unsigned)((seg & 3)*1024);                           \
          gload_lds16((const char*)VMEASB + s*32768 + (nt_)*4096 +             \
                        swzA(off + (unsigned)(lane*16)),                       \
                      lds_raw + (buf_)*12288 + s*4096 + (int)off);             \
        }                                                                      \
      } }

  STAGE_NT(0, 0)
  __syncthreads();   // sp zeroed + chunk0 staged+drained

  const int db0 = zh*64 + zq*16 + quad*4;

  for (int nt = 0; nt < 8; nt++){
    const int cb = nt & 1;
    if (nt < 7) STAGE_NT(nt+1, cb^1)     // other buffer; readers done at prev barrier
    int k = nt*16 + l15;
    f32x4 vR = *(const f32x4*)(VMEAS + k*128 + db0);
    f32x4 vI = *(const f32x4*)(VMEAS + 16384 + k*128 + db0);

    const char* bvr = lds_raw + cb*12288;
    const char* bvi = bvr + 4096;
    const char* bnv = bvr + 8192;

    f32x4 Ar = {0.f,0.f,0.f,0.f}, Ai = {0.f,0.f,0.f,0.f};
    #pragma unroll
    for (int ks = 0; ks < 4; ks++){
      unsigned a = swzA((unsigned)(l15*256 + ks*64 + quad*16));
      short8 b_vr = *(const short8*)(bvr + a);
      short8 b_vi = *(const short8*)(bvi + a);
      short8 b_nv = *(const short8*)(bnv + a);
      Ar = __builtin_amdgcn_mfma_f32_16x16x32_bf16(aR[ks], b_vr, Ar, 0, 0, 0);
      Ar = __builtin_amdgcn_mfma_f32_16x16x32_bf16(aI[ks], b_nv, Ar, 0, 0, 0);
      Ai = __builtin_amdgcn_mfma_f32_16x16x32_bf16(aR[ks], b_vi, Ai, 0, 0, 0);
      Ai = __builtin_amdgcn_mfma_f32_16x16x32_bf16(aI[ks], b_vr, Ai, 0, 0, 0);
    }

    float pv = 0.f;
    #pragma unroll
    for (int r = 0; r < 4; r++) pv += vR[r]*Ar[r] + vI[r]*Ai[r];
    pv += __shfl_xor(pv, 16, 64);
    pv += __shfl_xor(pv, 32, 64);
    if (quad == 0) atomicAdd(&sp[nt*16 + l15], pv);

    if (nt < 7){
      asm volatile("s_waitcnt vmcnt(0)" ::: "memory");  // chunk nt+1 landed
      __builtin_amdgcn_s_barrier();                     // + all reads of cb done
    }
  }
  #undef STAGE_NT

  // ---- head: h = relu(sp @ W1 + b1); logits = h @ W2 + b2; log_softmax ----
  __syncthreads();   // sp atomics visible
  if (tid < 64){
    float a0 = b1[tid], a1 = 0.f, a2 = 0.f, a3 = 0.f;
    for (int d = 0; d < 128; d += 4){
      a0 = fmaf(sp[d  ], W1[(d  )*64 + tid], a0);
      a1 = fmaf(sp[d+1], W1[(d+1)*64 + tid], a1);
      a2 = fmaf(sp[d+2], W1[(d+2)*64 + tid], a2);
      a3 = fmaf(sp[d+3], W1[(d+3)*64 + tid], a3);
    }
    hsh[tid] = fmaxf((a0 + a1) + (a2 + a3), 0.f);
  }
  __syncthreads();
  if (tid < 7){
    float a = b2[tid];
    for (int j = 0; j < 64; j++) a = fmaf(hsh[j], W2[j*7 + tid], a);
    lg[tid] = a;
  }
  __syncthreads();
  if (tid == 0){
    float M = -1e30f;
    for (int c = 0; c < 7; c++) M = fmaxf(M, lg[c]);
    float S = 0.f;
    for (int c = 0; c < 7; c++) S += __expf(lg[c] - M);
    mred[0] = M; mred[1] = logf(S);
  }
  __syncthreads();
  if (tid < 7) out[bt*7 + tid] = lg[tid] - mred[0] - mred[1];
}

// ---------------------------------------------------------------------------
extern "C" void kernel_launch(void* const* d_in, const int* in_sizes, int n_in,
                              void* d_out, int out_size, void* d_ws, size_t ws_size,
                              hipStream_t stream)
{
  (void)in_sizes; (void)n_in; (void)out_size; (void)ws_size;
  const float* xt   = (const float*)d_in[0];
  const float* xv   = (const float*)d_in[1];
  const float* xa   = (const float*)d_in[2];
  const float* Wpt  = (const float*)d_in[3];
  const float* bpt  = (const float*)d_in[4];
  const float* Wpv  = (const float*)d_in[5];
  const float* bpv  = (const float*)d_in[6];
  const float* Wpa  = (const float*)d_in[7];
  const float* bpa  = (const float*)d_in[8];
  const float* l1   = (const float*)d_in[9];
  const float* l2   = (const float*)d_in[10];
  const float* Wl1  = (const float*)d_in[11];
  const float* bl1  = (const float*)d_in[12];
  const float* Wl2  = (const float*)d_in[13];
  const float* bl2  = (const float*)d_in[14];
  const float* pht  = (const float*)d_in[15];
  const float* phv  = (const float*)d_in[16];
  const float* pha  = (const float*)d_in[17];
  const float* Wqkv = (const float*)d_in[18];
  const float* bqkv = (const float*)d_in[19];
  const float* Wo   = (const float*)d_in[20];
  const float* bo   = (const float*)d_in[21];
  const float* g1   = (const float*)d_in[22];
  const float* b1   = (const float*)d_in[23];
  const float* W1   = (const float*)d_in[24];
  const float* bf1  = (const float*)d_in[25];
  const float* W2   = (const float*)d_in[26];
  const float* bf2  = (const float*)d_in[27];
  const float* g2   = (const float*)d_in[28];
  const float* b2   = (const float*)d_in[29];
  const float* mr   = (const float*)d_in[30];
  const float* mi   = (const float*)d_in[31];
  const float* fcW1 = (const float*)d_in[32];
  const float* fcb1 = (const float*)d_in[33];
  const float* fcW2 = (const float*)d_in[34];
  const float* fcb2 = (const float*)d_in[35];
  float* out = (float*)d_out;

  // workspace layout (bytes) -- total ~34 MiB. All transposed weights = 2 layers.
  char* wsb = (char*)d_ws;
  short* Xb     = (short*)(wsb);                        // 16777216 B (bf16 X stream)
  bf16*  ATTO   = (bf16*) (wsb + 16777216);             // 16777216 B
  float* PURE   = (float*)(wsb + 33554432);             // 786432 B
  float* RNORM  = (float*)(wsb + 34340864);             // 4096 B
  float* LANGB  = (float*)(wsb + 34344960);             // 2048 B
  float* VMEAS  = (float*)(wsb + 34347008);             // 131072 B
  short* WqkvT  = (short*)(wsb + 34740224);             // 196608 B
  short* WoT    = (short*)(wsb + 34936832);             // 65536 B
  short* W1T    = (short*)(wsb + 35002368);             // 262144 B
  short* W2T    = (short*)(wsb + 35264512);             // 262144 B (chunk-major W2C)
  short* VMEASB = (short*)(wsb + 35526656);             // 98304 B

  prep_kernel<<<705, 128, 0, stream>>>(Wqkv, Wo, W1, W2, WqkvT, WoT, W1T, W2T,
                                       xt, xv, xa, Wpt, bpt, Wpv, bpv, Wpa, bpa,
                                       pht, phv, pha, PURE, RNORM,
                                       l1, l2, Wl1, bl1, Wl2, bl2, LANGB,
                                       mr, mi, VMEAS, VMEASB);

  rho_kernel<<<2048, 256, 0, stream>>>(PURE, RNORM, LANGB, Xb);

  for (int l = 0; l < 2; l++){
    attn_kernel<<<dim3(512, 4), 256, 0, stream>>>(Xb, WqkvT + (size_t)l*49152,
                                                  bqkv + (size_t)l*384, ATTO);
    proj_ffn_kernel<<<512, 256, 0, stream>>>(ATTO, Xb,
                                             WoT + (size_t)l*16384,
                                             bo + (size_t)l*128, g1 + (size_t)l*128,
                                             b1 + (size_t)l*128,
                                             W1T + (size_t)l*65536, bf1 + (size_t)l*512,
                                             W2T + (size_t)l*65536, bf2 + (size_t)l*128,
                                             g2 + (size_t)l*128, b2 + (size_t)l*128);
  }

  probs_head_kernel<<<256, 512, 0, stream>>>(Xb, VMEAS, VMEASB,
                                             fcW1, fcb1, fcW2, fcb2, out);
}

// Round 16
// 277.634 us; speedup vs baseline: 1.1046x; 1.1046x over previous
//
#include <hip/hip_runtime.h>
#include <hip/hip_bf16.h>

typedef __hip_bfloat16 bf16;
typedef short short8 __attribute__((ext_vector_type(8)));
typedef float f32x4 __attribute__((ext_vector_type(4)));
typedef unsigned uint2v __attribute__((ext_vector_type(2)));

__device__ __forceinline__ float b2f(bf16 v){ return __bfloat162float(v); }

__device__ __forceinline__ short f2bs(float f){
  union { __hip_bfloat16 b; short s; } u; u.b = __float2bfloat16(f); return u.s;
}
__device__ __forceinline__ float bs2f(short s){
  union { short s; __hip_bfloat16 b; } u; u.s = s; return __bfloat162float(u.b);
}
__device__ __forceinline__ unsigned pk2(float a, float b){
  return ((unsigned)(unsigned short)f2bs(a)) | (((unsigned)(unsigned short)f2bs(b)) << 16);
}

__device__ __forceinline__ float wred_sum(float v){
  #pragma unroll
  for (int o = 32; o > 0; o >>= 1) v += __shfl_xor(v, o, 64);
  return v;
}

// direct global->LDS DMA, 16B per lane. LDS dest = wave-uniform base + lane*16.
__device__ __forceinline__ void gload_lds16(const void* g, void* l){
  __builtin_amdgcn_global_load_lds((const __attribute__((address_space(1))) unsigned*)g,
                                   (__attribute__((address_space(3))) unsigned*)l, 16, 0, 0);
}

// XOR swizzles (involutions; key bits disjoint from modified bits).
// swzA: 256B-row buffers. 16-way -> 2-way conflict.
__device__ __forceinline__ unsigned swzA(unsigned a){ return a ^ (((a >> 8) & 7u) << 4); }
// swzB: 64B-row buffer (W2 chunk). 8-way -> 2-way conflict.
__device__ __forceinline__ unsigned swzB(unsigned a){ return a ^ (((a >> 7) & 3u) << 4); }

// ---------------------------------------------------------------------------
// modality helper (128 threads) -- r14 best: 4-chain loop, 768 blocks.
// FALSIFIED alternatives: r13 explicit unroll-8 (+12.7us, constrained the
// compiler's own pipelining); r15 batch-4-bt (+28.7us, collapsed modality
// parallelism 768->192 blocks, occupancy 3.4%). Block-level parallelism is
// what hides the W-load latency here -- do not reduce block count.
// ---------------------------------------------------------------------------
template<int DIMN>
__device__ void modality(const float* x, const float* W, const float* bia, const float* ph,
                         float* PURE, float* RNORM, int m, int bt, float* xs, float* red)
{
  int tid = threadIdx.x;
  for (int i = tid; i < DIMN; i += 128) xs[i] = x[bt*DIMN + i];
  __syncthreads();
  float a0 = 0.f, a1 = 0.f, a2 = 0.f, a3 = 0.f;
  int k = 0;
  for (; k + 4 <= DIMN; k += 4){
    a0 = fmaf(xs[k],   W[(k  )*128 + tid], a0);
    a1 = fmaf(xs[k+1], W[(k+1)*128 + tid], a1);
    a2 = fmaf(xs[k+2], W[(k+2)*128 + tid], a2);
    a3 = fmaf(xs[k+3], W[(k+3)*128 + tid], a3);
  }
  for (; k < DIMN; k++) a0 = fmaf(xs[k], W[k*128 + tid], a0);
  float acc = bia[tid] + ((a0 + a1) + (a2 + a3));
  float rep = fmaxf(acc, 0.f);
  float s = wred_sum(rep*rep);
  int wid = tid >> 6, lane = tid & 63;
  if (lane == 0) red[wid] = s;
  __syncthreads();
  float nrm = sqrtf(red[0] + red[1]);
  float amp = rep / fmaxf(nrm, 1e-12f);
  float p = ph[tid];
  PURE[bt*768 + m*128 + tid]       = amp * cosf(p);
  PURE[bt*768 + (3+m)*128 + tid]   = amp * sinf(p);
  if (tid == 0) RNORM[bt*4 + m] = nrm;
}

// ---------------------------------------------------------------------------
// Kernel 0 MERGED PREP (LDS-tiled 32x32 transposes; modality; lang; meas).
// ---------------------------------------------------------------------------
__global__ void prep_kernel(
    const float* __restrict__ Wqkv, const float* __restrict__ Wo,
    const float* __restrict__ W1, const float* __restrict__ W2,
    short* __restrict__ WqkvT, short* __restrict__ WoT,
    short* __restrict__ W1T, short* __restrict__ W2T,
    const float* xt, const float* xv, const float* xa,
    const float* Wpt, const float* bpt, const float* Wpv, const float* bpv,
    const float* Wpa, const float* bpa,
    const float* pht, const float* phv, const float* pha,
    float* PURE, float* RNORM,
    const float* l1, const float* l2,
    const float* Wl1, const float* bl1, const float* Wl2, const float* bl2,
    float* LANGB,
    const float* mr, const float* mi, float* VMEAS, short* VMEASB)
{
  __shared__ float xs[600];
  __shared__ float xs2a[300];
  __shared__ float red[4];
  __shared__ float tile[32][33];
  int b = blockIdx.x, tid = threadIdx.x;

  if (b < 384){
    int l = b / 192, bb = b - l*192;
    const float* in; short* out; int K, N, kt, nt_;
    bool isW2 = false;
    if (bb < 48)      { in = Wqkv; out = WqkvT; K = 128; N = 384; kt = bb & 3;  nt_ = bb >> 2; }
    else if (bb < 64) { int t = bb-48;  in = Wo; out = WoT; K = 128; N = 128; kt = t & 3;  nt_ = t >> 2; }
    else if (bb < 128){ int t = bb-64;  in = W1; out = W1T; K = 128; N = 512; kt = t & 3;  nt_ = t >> 2; }
    else              { int t = bb-128; in = W2; out = W2T; K = 512; N = 128; kt = t & 15; nt_ = t >> 4; isW2 = true; }
    int base = l * K * N;
    int kk0 = kt*32, nn0 = nt_*32;
    int r0 = tid >> 5, c = tid & 31;
    #pragma unroll
    for (int i = 0; i < 8; i++){
      int r = i*4 + r0;
      tile[r][c] = in[base + (kk0 + r)*N + nn0 + c];
    }
    __syncthreads();
    #pragma unroll
    for (int i = 0; i < 8; i++){
      int rr = i*4 + r0;
      float v = tile[c][rr];
      int oi;
      if (!isW2) oi = (nn0 + rr)*K + kk0 + c;
      else       oi = kt*4096 + (nn0 + rr)*32 + c;
      out[base + oi] = f2bs(v);
    }
    return;
  }
  if (b < 1152){
    int idx = b - 384;
    int bt = idx & 255, m = idx >> 8;
    if (m == 0)      modality<600>(xt, Wpt, bpt, pht, PURE, RNORM, 0, bt, xs, red);
    else if (m == 1) modality<342>(xv, Wpv, bpv, phv, PURE, RNORM, 1, bt, xs, red);
    else             modality<300>(xa, Wpa, bpa, pha, PURE, RNORM, 2, bt, xs, red);
    return;
  }
  if (b >= 1153){
    int k = b - 1153;
    float a = mr[k*128 + tid], bb2 = mi[k*128 + tid];
    float ws = wred_sum(a*a + bb2*bb2);
    int wid = tid >> 6, lane = tid & 63;
    if (lane == 0) red[wid] = ws;
    __syncthreads();
    float inv = 1.f / fmaxf(sqrtf(red[0] + red[1]), 1e-12f);
    float vr = a * inv, vi = bb2 * inv;
    int i = k*128 + tid;
    VMEAS[i]          = vr;
    VMEAS[16384 + i]  = vi;
    VMEASB[i]         = f2bs(vr);
    VMEASB[16384 + i] = f2bs(vi);
    VMEASB[32768 + i] = f2bs(-vi);
    return;
  }
  // ---- lang path (single block, b == 1152) ----
  for (int i = tid; i < 300; i += 128){ xs[i] = l1[i]; xs2a[i] = l2[i]; }
  __syncthreads();
  float p10=0,p11=0,p12=0,p13=0, p20=0,p21=0,p22=0,p23=0;
  for (int k = 0; k < 300; k += 4){
    p10 = fmaf(xs[k],    Wl1[(k  )*128+tid], p10);
    p11 = fmaf(xs[k+1],  Wl1[(k+1)*128+tid], p11);
    p12 = fmaf(xs[k+2],  Wl1[(k+2)*128+tid], p12);
    p13 = fmaf(xs[k+3],  Wl1[(k+3)*128+tid], p13);
    p20 = fmaf(xs2a[k],  Wl2[(k  )*128+tid], p20);
    p21 = fmaf(xs2a[k+1],Wl2[(k+1)*128+tid], p21);
    p22 = fmaf(xs2a[k+2],Wl2[(k+2)*128+tid], p22);
    p23 = fmaf(xs2a[k+3],Wl2[(k+3)*128+tid], p23);
  }
  float a1 = bl1[tid] + ((p10+p11)+(p12+p13));
  float a2 = bl2[tid] + ((p20+p21)+(p22+p23));
  a1 = fmaxf(a1, 0.f); a2 = fmaxf(a2, 0.f);
  int wid = tid >> 6, lane = tid & 63;
  float s1 = wred_sum(a1*a1), s2 = wred_sum(a2*a2);
  if (lane == 0){ red[wid] = s1; red[2+wid] = s2; }
  __syncthreads();
  float n1 = sqrtf(red[0] + red[1]);
  float n2 = sqrtf(red[2] + red[3]);
  float lamp1 = a1 / fmaxf(n1, 1e-12f);
  float lamp2 = a2 / fmaxf(n2, 1e-12f);
  float ph = pht[tid];
  float c = cosf(ph), s = sinf(ph);
  const float s2c = 0.70710678118654752f;
  float h1r = (lamp1*c + lamp1*s)*s2c, h1i = (lamp1*c - lamp1*s)*s2c;
  float h2r = (lamp2*c + lamp2*s)*s2c, h2i = (lamp2*c - lamp2*s)*s2c;
  float er = h1r*h2r - h1i*h2i;
  float ei = h1r*h2i + h1i*h2r;
  __syncthreads();
  float se = wred_sum(er*er + ei*ei);
  if (lane == 0) red[wid] = se;
  __syncthreads();
  float en = fmaxf(sqrtf(red[0] + red[1]), 1e-12f);
  LANGB[tid]       = er / en;
  LANGB[128 + tid] = ei / en;
  if (tid == 0) LANGB[256] = n1;
}

// ---------------------------------------------------------------------------
// Kernel 3: weighted sum of rank-1 density matrices -> Xb (bf16).
// grid 2048: each block computes a 2048-elem quarter (32 waves/CU).
// bt = b & 255 keeps XCD alignment.
// ---------------------------------------------------------------------------
__global__ __launch_bounds__(256) void rho_kernel(const float* PURE, const float* RNORM,
                                                  const float* LANGB, short* Xb)
{
  __shared__ float rv[4][128], iv[4][128], wsm[4];
  int bt = blockIdx.x & 255, quarter = blockIdx.x >> 8;   // 0..7
  int tid = threadIdx.x;
  for (int i = tid; i < 1024; i += 256){
    int d = i & 127;
    if (i < 768){ int m = i >> 7; float v = PURE[bt*768 + i];
                  if (m < 3) rv[m][d] = v; else iv[m-3][d] = v; }
    else if (i < 896) rv[3][d] = LANGB[d];
    else              iv[3][d] = LANGB[128 + d];
  }
  if (tid == 0){
    float n0 = RNORM[bt*4+0], n1 = RNORM[bt*4+1], n2 = RNORM[bt*4+2], n3 = LANGB[256];
    float mx = fmaxf(fmaxf(n0, n1), fmaxf(n2, n3));
    float e0 = __expf(n0-mx), e1 = __expf(n1-mx), e2 = __expf(n2-mx), e3 = __expf(n3-mx);
    float inv = 1.f / (e0+e1+e2+e3);
    wsm[0]=e0*inv; wsm[1]=e1*inv; wsm[2]=e2*inv; wsm[3]=e3*inv;
  }
  __syncthreads();
  float w0 = wsm[0], w1 = wsm[1], w2 = wsm[2], w3 = wsm[3];
  int lo = quarter*2048, hi = lo + 2048;
  for (int idx = lo + tid; idx < hi; idx += 256){
    int d = idx >> 7, e = idx & 127;
    float rr = 0.f, ri = 0.f;
    {
      float rd=rv[0][d], re=rv[0][e], id=iv[0][d], ie=iv[0][e];
      rr = fmaf(w0, rd*re + id*ie, rr); ri = fmaf(w0, id*re - rd*ie, ri);
    }{
      float rd=rv[1][d], re=rv[1][e], id=iv[1][d], ie=iv[1][e];
      rr = fmaf(w1, rd*re + id*ie, rr); ri = fmaf(w1, id*re - rd*ie, ri);
    }{
      float rd=rv[2][d], re=rv[2][e], id=iv[2][d], ie=iv[2][e];
      rr = fmaf(w2, rd*re + id*ie, rr); ri = fmaf(w2, id*re - rd*ie, ri);
    }{
      float rd=rv[3][d], re=rv[3][e], id=iv[3][d], ie=iv[3][e];
      rr = fmaf(w3, rd*re + id*ie, rr); ri = fmaf(w3, id*re - rd*ie, ri);
    }
    Xb[(size_t)bt*16384 + idx]        = f2bs(rr);
    Xb[(size_t)(256+bt)*16384 + idx]  = f2bs(ri);
  }
}

// ---------------------------------------------------------------------------
// Kernel 4a: fused MHA per (n, head). grid (512,4), block 256.  [r8 best]
// v5 swapped QK^T softmax + packed P stores. LDS 43.5KB, 3 blocks/CU.
// ---------------------------------------------------------------------------
__global__ __launch_bounds__(256) void attn_kernel(const short* __restrict__ Xb,
    const short* __restrict__ WqkvT, const float* __restrict__ bqkv,
    bf16* __restrict__ ATTO)
{
  __shared__ __align__(16) char lds_raw[43520];
  short* Vt = (short*)(lds_raw);           // [32][136]
  short* Qs = (short*)(lds_raw + 8704);    // [128][40]
  short* Ks = (short*)(lds_raw + 18944);   // [128][40]
  short* Ps = (short*)(lds_raw + 8704);    // [128][136] row-major P[q][k]

  const int n = blockIdx.x, h = blockIdx.y;
  const int tid = threadIdx.x;
  const int wid = tid >> 6, lane = tid & 63;
  const int l15 = lane & 15, quad = lane >> 4;
  const int wb = __builtin_amdgcn_readfirstlane(wid);
  const short* xn = Xb + (size_t)n*16384;
  const char* Wbase = (const char*)WqkvT;

  short8 afr[2][4];
  #pragma unroll
  for (int mi = 0; mi < 2; mi++)
    #pragma unroll
    for (int ks = 0; ks < 4; ks++){
      int row = (wid*2 + mi)*16 + l15;
      afr[mi][ks] = *(const short8*)(xn + row*128 + ks*32 + quad*8);
    }
  #pragma unroll
  for (int j = 0; j < 6; j++){
    int seg = wb*6 + j;                 // 0..23
    int slab = seg >> 3;                // 0=q,1=k,2=v
    unsigned off = (unsigned)((seg & 7)*1024);
    unsigned gbase = (unsigned)((slab*128 + h*32)*256);
    gload_lds16(Wbase + gbase + swzA(off + (unsigned)(lane*16)),
                lds_raw + seg*1024);
  }
  __syncthreads();

  f32x4 acc[2][6];
  #pragma unroll
  for (int mi = 0; mi < 2; mi++)
    #pragma unroll
    for (int nt = 0; nt < 6; nt++){
      f32x4 z = {0.f, 0.f, 0.f, 0.f}; acc[mi][nt] = z;
    }

  #pragma unroll
  for (int ks = 0; ks < 4; ks++){
    #pragma unroll
    for (int nt = 0; nt < 6; nt++){
      int slab = nt >> 1;
      int col = (nt & 1)*16 + l15;
      unsigned a = (unsigned)(col*256 + ks*64 + quad*16);
      short8 bfr = *(const short8*)(lds_raw + slab*8192 + swzA(a));
      #pragma unroll
      for (int mi = 0; mi < 2; mi++)
        acc[mi][nt] = __builtin_amdgcn_mfma_f32_16x16x32_bf16(afr[mi][ks], bfr, acc[mi][nt], 0, 0, 0);
    }
  }
  __syncthreads();

  #pragma unroll
  for (int nt = 0; nt < 6; nt++){
    int sec = nt >> 1;
    int cl = (nt & 1)*16 + l15;
    float bias = bqkv[sec*128 + h*32 + cl];
    #pragma unroll
    for (int mi = 0; mi < 2; mi++){
      int rowb = (wid*2 + mi)*16 + quad*4;
      #pragma unroll
      for (int r = 0; r < 4; r++){
        float v = acc[mi][nt][r] + bias;
        int row = rowb + r;
        if (sec == 0)      Qs[row*40 + cl] = f2bs(v * 0.17677669529663687f);
        else if (sec == 1) Ks[row*40 + cl] = f2bs(v);
        else               Vt[cl*136 + row] = f2bs(v);
      }
    }
  }
  __syncthreads();

  // ---- QK^T SWAPPED: s2[kt][qt] = S^T tile; lane holds S[q][k-slice] ----
  f32x4 s2[8][2];
  {
    short8 qf[2];
    #pragma unroll
    for (int qt = 0; qt < 2; qt++){
      int row = (wid*2 + qt)*16 + l15;
      qf[qt] = *(const short8*)(Qs + row*40 + quad*8);
    }
    #pragma unroll
    for (int kt = 0; kt < 8; kt++){
      int kr = kt*16 + l15;
      short8 kf = *(const short8*)(Ks + kr*40 + quad*8);
      #pragma unroll
      for (int qt = 0; qt < 2; qt++){
        f32x4 z = {0.f, 0.f, 0.f, 0.f};
        s2[kt][qt] = __builtin_amdgcn_mfma_f32_16x16x32_bf16(kf, qf[qt], z, 0, 0, 0);
      }
    }
  }

  // ---- softmax over k: per qt, in-lane 32-value reduce + 2 cross-quad shfls ----
  #pragma unroll
  for (int qt = 0; qt < 2; qt++){
    float mx = -1e30f;
    #pragma unroll
    for (int kt = 0; kt < 8; kt++)
      #pragma unroll
      for (int r = 0; r < 4; r++) mx = fmaxf(mx, s2[kt][qt][r]);
    mx = fmaxf(mx, __shfl_xor(mx, 16, 64));
    mx = fmaxf(mx, __shfl_xor(mx, 32, 64));
    float sum = 0.f;
    #pragma unroll
    for (int kt = 0; kt < 8; kt++)
      #pragma unroll
      for (int r = 0; r < 4; r++){
        float p = __expf(s2[kt][qt][r] - mx);
        s2[kt][qt][r] = p; sum += p;
      }
    sum += __shfl_xor(sum, 16, 64);
    sum += __shfl_xor(sum, 32, 64);
    float inv = 1.f / sum;
    #pragma unroll
    for (int kt = 0; kt < 8; kt++)
      #pragma unroll
      for (int r = 0; r < 4; r++) s2[kt][qt][r] *= inv;
  }
  __syncthreads();   // Qs/Ks reads done -> Ps may overlay

  // ---- packed P stores: 4 consecutive k per lane -> one b64 write ----
  #pragma unroll
  for (int kt = 0; kt < 8; kt++){
    #pragma unroll
    for (int qt = 0; qt < 2; qt++){
      int q  = (wid*2 + qt)*16 + l15;
      int k0 = kt*16 + quad*4;
      uint2v v;
      v.x = pk2(s2[kt][qt][0], s2[kt][qt][1]);
      v.y = pk2(s2[kt][qt][2], s2[kt][qt][3]);
      *(uint2v*)((char*)Ps + (unsigned)(q*272 + k0*2)) = v;
    }
  }
  __syncthreads();

  f32x4 o_[2][2];
  #pragma unroll
  for (int mi = 0; mi < 2; mi++)
    #pragma unroll
    for (int n2 = 0; n2 < 2; n2++){
      f32x4 z = {0.f, 0.f, 0.f, 0.f}; o_[mi][n2] = z;
    }
  #pragma unroll
  for (int ks = 0; ks < 4; ks++){
    short8 pf[2];
    #pragma unroll
    for (int mi = 0; mi < 2; mi++){
      int row = (wid*2 + mi)*16 + l15;
      pf[mi] = *(const short8*)(Ps + row*136 + ks*32 + quad*8);
    }
    #pragma unroll
    for (int n2 = 0; n2 < 2; n2++){
      short8 vf = *(const short8*)(Vt + (n2*16 + l15)*136 + ks*32 + quad*8);
      #pragma unroll
      for (int mi = 0; mi < 2; mi++)
        o_[mi][n2] = __builtin_amdgcn_mfma_f32_16x16x32_bf16(pf[mi], vf, o_[mi][n2], 0, 0, 0);
    }
  }
  bf16* on = ATTO + (size_t)n*16384;
  #pragma unroll
  for (int mi = 0; mi < 2; mi++){
    int rowb = (wid*2 + mi)*16 + quad*4;
    #pragma unroll
    for (int n2 = 0; n2 < 2; n2++){
      int col = h*32 + n2*16 + l15;
      #pragma unroll
      for (int r = 0; r < 4; r++)
        on[(rowb + r)*128 + col] = __float2bfloat16(o_[mi][n2][r]);
    }
  }
}

// ---------------------------------------------------------------------------
// Kernel 4bc FUSED: grid 512, block 256, 4 waves x 32 rows.
// v7 single-barrier chunk loop: per chunk { STAGE(c+1, other-buf);
// compute(c); vmcnt(0); barrier }.
// ---------------------------------------------------------------------------
__global__ __launch_bounds__(256, 2) void proj_ffn_kernel(const bf16* __restrict__ SRC,
    short* __restrict__ Xb, const short* __restrict__ WoT,
    const float* __restrict__ bo, const float* __restrict__ g1v,
    const float* __restrict__ bb1,
    const short* __restrict__ W1T, const float* __restrict__ bf1,
    const short* __restrict__ W2C, const float* __restrict__ bf2,
    const float* __restrict__ g2v, const float* __restrict__ bb2)
{
  __shared__ __align__(16) char lds_raw[65536];
  __shared__ float bf1L[512];
  const int n = blockIdx.x, tid = threadIdx.x;
  const int wid = tid >> 6, lane = tid & 63;
  const int l15 = lane & 15, quad = lane >> 4;
  const int wb = __builtin_amdgcn_readfirstlane(wid);
  const short* an = (const short*)SRC + (size_t)n*16384;
  short* xn = Xb + (size_t)n*16384;
  char* XsB = lds_raw + 32768;
  short* Hs = (short*)(lds_raw + 32768);

  // ---- t0: A-fragments (ATTO) to regs; stage WoT + residual(Xs); bf1->LDS ----
  short8 af[2][4];
  #pragma unroll
  for (int mi = 0; mi < 2; mi++)
    #pragma unroll
    for (int ks = 0; ks < 4; ks++){
      int row = wid*32 + mi*16 + l15;
      af[mi][ks] = *(const short8*)(an + row*128 + ks*32 + quad*8);
    }
  #pragma unroll
  for (int j = 0; j < 8; j++){
    unsigned L = (unsigned)(j*4096 + wb*1024 + lane*16);
    gload_lds16((const char*)WoT + swzA(L), lds_raw + (j*4096 + wb*1024));
    gload_lds16((const char*)xn  + swzA(L), XsB + (j*4096 + wb*1024));
  }
  for (int i = tid; i < 512; i += 256) bf1L[i] = bf1[i];
  float bov[8], g1a[8], b1a[8];
  #pragma unroll
  for (int nt = 0; nt < 8; nt++){
    int col = nt*16 + l15;
    bov[nt] = bo[col]; g1a[nt] = g1v[col]; b1a[nt] = bb1[col];
  }
  __syncthreads();   // WoT + Xs staged, bf1L visible

  // ---- Wo projection from LDS weights ----
  f32x4 Y[2][8];
  #pragma unroll
  for (int mi = 0; mi < 2; mi++)
    #pragma unroll
    for (int nt = 0; nt < 8; nt++){ f32x4 z = {0.f,0.f,0.f,0.f}; Y[mi][nt] = z; }
  #pragma unroll
  for (int ks = 0; ks < 4; ks++){
    #pragma unroll
    for (int nt = 0; nt < 8; nt++){
      unsigned a = (unsigned)((nt*16 + l15)*256 + ks*64 + quad*16);
      short8 bh = *(const short8*)(lds_raw + swzA(a));
      #pragma unroll
      for (int mi = 0; mi < 2; mi++)
        Y[mi][nt] = __builtin_amdgcn_mfma_f32_16x16x32_bf16(af[mi][ks], bh, Y[mi][nt], 0, 0, 0);
    }
  }
  __syncthreads();   // WoT region free for chunk buffers

  // ---- issue stage of FFN chunk 0 into buf0 ----
  #pragma unroll
  for (int j = 0; j < 2; j++){
    unsigned L = (unsigned)(j*4096 + wb*1024 + lane*16);
    gload_lds16((const char*)W1T + swzA(L), lds_raw + (j*4096 + wb*1024));
    gload_lds16((const char*)W2C + swzB(L), lds_raw + (8192 + j*4096 + wb*1024));
  }

  // ---- residual + LN1 (residual from Xs; output -> Xs bounce + packed regs) ----
  unsigned yv1p[2][4][4];
  #pragma unroll
  for (int mi = 0; mi < 2; mi++){
    #pragma unroll
    for (int r = 0; r < 4; r++){
      int row = wid*32 + mi*16 + quad*4 + r;
      float yv[8]; float S = 0.f, Q = 0.f;
      #pragma unroll
      for (int nt = 0; nt < 8; nt++){
        int col = nt*16 + l15;
        float res = bs2f(*(const short*)(XsB + swzA((unsigned)(row*256 + col*2))));
        float y = Y[mi][nt][r] + bov[nt] + res;
        yv[nt] = y; S += y; Q += y*y;
      }
      #pragma unroll
      for (int o = 1; o < 16; o <<= 1){ S += __shfl_xor(S, o, 64); Q += __shfl_xor(Q, o, 64); }
      float m = S * (1.f/128.f);
      float var = Q * (1.f/128.f) - m*m;
      float inv = rsqrtf(var + 1e-5f);
      #pragma unroll
      for (int nt = 0; nt < 8; nt++){
        int col = nt*16 + l15;
        short ob = f2bs((yv[nt] - m) * inv * g1a[nt] + b1a[nt]);
        *(short*)(XsB + swzA((unsigned)(row*256 + col*2))) = ob;
        unsigned u = (unsigned)(unsigned short)ob;
        if ((nt & 1) == 0) yv1p[mi][r][nt>>1] = u;
        else               yv1p[mi][r][nt>>1] |= (u << 16);
      }
    }
  }

  // ---- A-fragments of LN1 output (wave-private rows, via Xs bounce) ----
  short8 af2[2][4];
  #pragma unroll
  for (int mi = 0; mi < 2; mi++)
    #pragma unroll
    for (int ks = 0; ks < 4; ks++){
      int row = wid*32 + mi*16 + l15;
      unsigned a = (unsigned)(row*256 + ks*64 + quad*16);
      af2[mi][ks] = *(const short8*)(XsB + swzA(a));
    }
  __syncthreads();   // chunk0 staged(+drained) + all waves past Xs reads (Hs overlays)

  // ---- FFN: 16 chunks, double-buffered, ONE barrier per chunk ----
  f32x4 Y2[2][8];
  #pragma unroll
  for (int mi = 0; mi < 2; mi++)
    #pragma unroll
    for (int nt = 0; nt < 8; nt++){ f32x4 z = {0.f,0.f,0.f,0.f}; Y2[mi][nt] = z; }

  for (int c = 0; c < 16; c++){
    const int cb = c & 1;
    if (c < 15){
      const int nb = cb ^ 1;
      #pragma unroll
      for (int j = 0; j < 2; j++){
        unsigned L = (unsigned)(j*4096 + wb*1024 + lane*16);
        gload_lds16((const char*)W1T + (unsigned)((c+1)*8192) + swzA(L),
                    lds_raw + (nb*16384 + j*4096 + wb*1024));
        gload_lds16((const char*)W2C + (unsigned)((c+1)*8192) + swzB(L),
                    lds_raw + (nb*16384 + 8192 + j*4096 + wb*1024));
      }
    }
    const char* bW1 = lds_raw + cb*16384;
    const char* bW2 = lds_raw + cb*16384 + 8192;

    f32x4 Hc[2][2];
    #pragma unroll
    for (int mi = 0; mi < 2; mi++)
      #pragma unroll
      for (int nt2 = 0; nt2 < 2; nt2++){ f32x4 z = {0.f,0.f,0.f,0.f}; Hc[mi][nt2] = z; }
    #pragma unroll
    for (int ks = 0; ks < 4; ks++){
      #pragma unroll
      for (int nt2 = 0; nt2 < 2; nt2++){
        unsigned a = (unsigned)((nt2*16 + l15)*256 + ks*64 + quad*16);
        short8 bh = *(const short8*)(bW1 + swzA(a));
        #pragma unroll
        for (int mi = 0; mi < 2; mi++)
          Hc[mi][nt2] = __builtin_amdgcn_mfma_f32_16x16x32_bf16(af2[mi][ks], bh, Hc[mi][nt2], 0, 0, 0);
      }
    }
    float b1v0 = bf1L[c*32 + l15];
    float b1v1 = bf1L[c*32 + 16 + l15];
    #pragma unroll
    for (int nt2 = 0; nt2 < 2; nt2++){
      int col = nt2*16 + l15;
      float b1v = nt2 ? b1v1 : b1v0;
      #pragma unroll
      for (int mi = 0; mi < 2; mi++){
        int rowb = wid*32 + mi*16 + quad*4;
        #pragma unroll
        for (int r = 0; r < 4; r++)
          Hs[(rowb + r)*40 + col] = f2bs(fmaxf(Hc[mi][nt2][r] + b1v, 0.f));
      }
    }
    short8 ph[2];
    #pragma unroll
    for (int mi = 0; mi < 2; mi++){
      int row = wid*32 + mi*16 + l15;
      ph[mi] = *(const short8*)(Hs + row*40 + quad*8);
    }
    #pragma unroll
    for (int nt = 0; nt < 8; nt++){
      unsigned a = (unsigned)((nt*16 + l15)*64 + quad*16);
      short8 bh = *(const short8*)(bW2 + swzB(a));
      #pragma unroll
      for (int mi = 0; mi < 2; mi++)
        Y2[mi][nt] = __builtin_amdgcn_mfma_f32_16x16x32_bf16(ph[mi], bh, Y2[mi][nt], 0, 0, 0);
    }
    if (c < 15){
      asm volatile("s_waitcnt vmcnt(0)" ::: "memory");  // chunk c+1 landed
      __builtin_amdgcn_s_barrier();                     // + all reads of cb done
    }
  }

  // ---- residual (packed regs) + LN2 -> xn ----
  {
    float b2v[8], gv[8], bbv[8];
    #pragma unroll
    for (int nt = 0; nt < 8; nt++){
      int col = nt*16 + l15;
      b2v[nt] = bf2[col]; gv[nt] = g2v[col]; bbv[nt] = bb2[col];
    }
    #pragma unroll
    for (int mi = 0; mi < 2; mi++){
      #pragma unroll
      for (int r = 0; r < 4; r++){
        int row = wid*32 + mi*16 + quad*4 + r;
        float yv[8]; float S = 0.f, Q = 0.f;
        #pragma unroll
        for (int nt = 0; nt < 8; nt++){
          unsigned u = yv1p[mi][r][nt>>1];
          short rs = (short)((nt & 1) ? (u >> 16) : (u & 0xffffu));
          float y = Y2[mi][nt][r] + b2v[nt] + bs2f(rs);
          yv[nt] = y; S += y; Q += y*y;
        }
        #pragma unroll
        for (int o = 1; o < 16; o <<= 1){ S += __shfl_xor(S, o, 64); Q += __shfl_xor(Q, o, 64); }
        float m = S * (1.f/128.f);
        float var = Q * (1.f/128.f) - m*m;
        float inv = rsqrtf(var + 1e-5f);
        #pragma unroll
        for (int nt = 0; nt < 8; nt++){
          int col = nt*16 + l15;
          xn[row*128 + col] = f2bs((yv[nt] - m) * inv * gv[nt] + bbv[nt]);
        }
      }
    }
  }
}

// ---------------------------------------------------------------------------
// Kernel 5: probs + head FUSED. grid 256 (bt), block 512 (8 waves).
// v4 single-barrier chunk loop.
// ---------------------------------------------------------------------------
__global__ __launch_bounds__(512) void probs_head_kernel(const short* __restrict__ Xb,
    const float* __restrict__ VMEAS, const short* __restrict__ VMEASB,
    const float* __restrict__ W1, const float* __restrict__ b1,
    const float* __restrict__ W2, const float* __restrict__ b2,
    float* __restrict__ out)
{
  __shared__ __align__(16) char lds_raw[24576];   // dbuf[2] x {vr,vi,nvi} 4KB each
  __shared__ float sp[128];
  __shared__ float hsh[64];
  __shared__ float lg[7];
  __shared__ float mred[2];
  const int bt = blockIdx.x, tid = threadIdx.x;
  const int wid = tid >> 6, lane = tid & 63;
  const int l15 = lane & 15, quad = lane >> 4;
  const int wb = __builtin_amdgcn_readfirstlane(wid);
  const int zh = wb >> 2;          // z-half (0: rows 0-63, 1: rows 64-127)
  const int zq = wb & 3;           // 16-row quarter within the half
  const short* R = Xb + (size_t)bt*16384;
  const short* I = Xb + (size_t)(256+bt)*16384;

  if (tid < 128) sp[tid] = 0.f;

  // ---- A-fragments (single z-half per wave) ----
  const int drow = zh*64 + zq*16 + l15;
  short8 aR[4], aI[4];
  #pragma unroll
  for (int ks = 0; ks < 4; ks++){
    aR[ks] = *(const short8*)(R + drow*128 + ks*32 + quad*8);
    aI[ks] = *(const short8*)(I + drow*128 + ks*32 + quad*8);
  }

  // stage chunk nt (12KB = 12 x 1KB segs, 2 per wave for waves 0..5)
  #define STAGE_NT(nt_, buf_)                                                  \
    { _Pragma("unroll")                                                        \
      for (int j = 0; j < 2; j++){                                             \
        int seg = wb*2 + j;            /* 0..15, use 0..11 */                  \
        if (seg < 12){                                                         \
          int s = seg >> 2;            /* slab 0..2 */                         \
          unsigned off = (unsigned)((seg & 3)*1024);                           \
          gload_lds16((const char*)VMEASB + s*32768 + (nt_)*4096 +             \
                        swzA(off + (unsigned)(lane*16)),                       \
                      lds_raw + (buf_)*12288 + s*4096 + (int)off);             \
        }                                                                      \
      } }

  STAGE_NT(0, 0)
  __syncthreads();   // sp zeroed + chunk0 staged+drained

  const int db0 = zh*64 + zq*16 + quad*4;

  for (int nt = 0; nt < 8; nt++){
    const int cb = nt & 1;
    if (nt < 7) STAGE_NT(nt+1, cb^1)     // other buffer; readers done at prev barrier
    int k = nt*16 + l15;
    f32x4 vR = *(const f32x4*)(VMEAS + k*128 + db0);
    f32x4 vI = *(const f32x4*)(VMEAS + 16384 + k*128 + db0);

    const char* bvr = lds_raw + cb*12288;
    const char* bvi = bvr + 4096;
    const char* bnv = bvr + 8192;

    f32x4 Ar = {0.f,0.f,0.f,0.f}, Ai = {0.f,0.f,0.f,0.f};
    #pragma unroll
    for (int ks = 0; ks < 4; ks++){
      unsigned a = swzA((unsigned)(l15*256 + ks*64 + quad*16));
      short8 b_vr = *(const short8*)(bvr + a);
      short8 b_vi = *(const short8*)(bvi + a);
      short8 b_nv = *(const short8*)(bnv + a);
      Ar = __builtin_amdgcn_mfma_f32_16x16x32_bf16(aR[ks], b_vr, Ar, 0, 0, 0);
      Ar = __builtin_amdgcn_mfma_f32_16x16x32_bf16(aI[ks], b_nv, Ar, 0, 0, 0);
      Ai = __builtin_amdgcn_mfma_f32_16x16x32_bf16(aR[ks], b_vi, Ai, 0, 0, 0);
      Ai = __builtin_amdgcn_mfma_f32_16x16x32_bf16(aI[ks], b_vr, Ai, 0, 0, 0);
    }

    float pv = 0.f;
    #pragma unroll
    for (int r = 0; r < 4; r++) pv += vR[r]*Ar[r] + vI[r]*Ai[r];
    pv += __shfl_xor(pv, 16, 64);
    pv += __shfl_xor(pv, 32, 64);
    if (quad == 0) atomicAdd(&sp[nt*16 + l15], pv);

    if (nt < 7){
      asm volatile("s_waitcnt vmcnt(0)" ::: "memory");  // chunk nt+1 landed
      __builtin_amdgcn_s_barrier();                     // + all reads of cb done
    }
  }
  #undef STAGE_NT

  // ---- head: h = relu(sp @ W1 + b1); logits = h @ W2 + b2; log_softmax ----
  __syncthreads();   // sp atomics visible
  if (tid < 64){
    float a0 = b1[tid], a1 = 0.f, a2 = 0.f, a3 = 0.f;
    for (int d = 0; d < 128; d += 4){
      a0 = fmaf(sp[d  ], W1[(d  )*64 + tid], a0);
      a1 = fmaf(sp[d+1], W1[(d+1)*64 + tid], a1);
      a2 = fmaf(sp[d+2], W1[(d+2)*64 + tid], a2);
      a3 = fmaf(sp[d+3], W1[(d+3)*64 + tid], a3);
    }
    hsh[tid] = fmaxf((a0 + a1) + (a2 + a3), 0.f);
  }
  __syncthreads();
  if (tid < 7){
    float a = b2[tid];
    for (int j = 0; j < 64; j++) a = fmaf(hsh[j], W2[j*7 + tid], a);
    lg[tid] = a;
  }
  __syncthreads();
  if (tid == 0){
    float M = -1e30f;
    for (int c = 0; c < 7; c++) M = fmaxf(M, lg[c]);
    float S = 0.f;
    for (int c = 0; c < 7; c++) S += __expf(lg[c] - M);
    mred[0] = M; mred[1] = logf(S);
  }
  __syncthreads();
  if (tid < 7) out[bt*7 + tid] = lg[tid] - mred[0] - mred[1];
}

// ---------------------------------------------------------------------------
extern "C" void kernel_launch(void* const* d_in, const int* in_sizes, int n_in,
                              void* d_out, int out_size, void* d_ws, size_t ws_size,
                              hipStream_t stream)
{
  (void)in_sizes; (void)n_in; (void)out_size; (void)ws_size;
  const float* xt   = (const float*)d_in[0];
  const float* xv   = (const float*)d_in[1];
  const float* xa   = (const float*)d_in[2];
  const float* Wpt  = (const float*)d_in[3];
  const float* bpt  = (const float*)d_in[4];
  const float* Wpv  = (const float*)d_in[5];
  const float* bpv  = (const float*)d_in[6];
  const float* Wpa  = (const float*)d_in[7];
  const float* bpa  = (const float*)d_in[8];
  const float* l1   = (const float*)d_in[9];
  const float* l2   = (const float*)d_in[10];
  const float* Wl1  = (const float*)d_in[11];
  const float* bl1  = (const float*)d_in[12];
  const float* Wl2  = (const float*)d_in[13];
  const float* bl2  = (const float*)d_in[14];
  const float* pht  = (const float*)d_in[15];
  const float* phv  = (const float*)d_in[16];
  const float* pha  = (const float*)d_in[17];
  const float* Wqkv = (const float*)d_in[18];
  const float* bqkv = (const float*)d_in[19];
  const float* Wo   = (const float*)d_in[20];
  const float* bo   = (const float*)d_in[21];
  const float* g1   = (const float*)d_in[22];
  const float* b1   = (const float*)d_in[23];
  const float* W1   = (const float*)d_in[24];
  const float* bf1  = (const float*)d_in[25];
  const float* W2   = (const float*)d_in[26];
  const float* bf2  = (const float*)d_in[27];
  const float* g2   = (const float*)d_in[28];
  const float* b2   = (const float*)d_in[29];
  const float* mr   = (const float*)d_in[30];
  const float* mi   = (const float*)d_in[31];
  const float* fcW1 = (const float*)d_in[32];
  const float* fcb1 = (const float*)d_in[33];
  const float* fcW2 = (const float*)d_in[34];
  const float* fcb2 = (const float*)d_in[35];
  float* out = (float*)d_out;

  // workspace layout (bytes) -- total ~34 MiB. All transposed weights = 2 layers.
  char* wsb = (char*)d_ws;
  short* Xb     = (short*)(wsb);                        // 16777216 B (bf16 X stream)
  bf16*  ATTO   = (bf16*) (wsb + 16777216);             // 16777216 B
  float* PURE   = (float*)(wsb + 33554432);             // 786432 B
  float* RNORM  = (float*)(wsb + 34340864);             // 4096 B
  float* LANGB  = (float*)(wsb + 34344960);             // 2048 B
  float* VMEAS  = (float*)(wsb + 34347008);             // 131072 B
  float* PROBS  = (float*)(wsb + 34478080);             // 262144 B (unused)
  short* WqkvT  = (short*)(wsb + 34740224);             // 196608 B
  short* WoT    = (short*)(wsb + 34936832);             // 65536 B
  short* W1T    = (short*)(wsb + 35002368);             // 262144 B
  short* W2T    = (short*)(wsb + 35264512);             // 262144 B (chunk-major W2C)
  short* VMEASB = (short*)(wsb + 35526656);             // 98304 B
  (void)PROBS;

  prep_kernel<<<1281, 128, 0, stream>>>(Wqkv, Wo, W1, W2, WqkvT, WoT, W1T, W2T,
                                        xt, xv, xa, Wpt, bpt, Wpv, bpv, Wpa, bpa,
                                        pht, phv, pha, PURE, RNORM,
                                        l1, l2, Wl1, bl1, Wl2, bl2, LANGB,
                                        mr, mi, VMEAS, VMEASB);

  rho_kernel<<<2048, 256, 0, stream>>>(PURE, RNORM, LANGB, Xb);

  for (int l = 0; l < 2; l++){
    attn_kernel<<<dim3(512, 4), 256, 0, stream>>>(Xb, WqkvT + (size_t)l*49152,
                                                  bqkv + (size_t)l*384, ATTO);
    proj_ffn_kernel<<<512, 256, 0, stream>>>(ATTO, Xb,
                                             WoT + (size_t)l*16384,
                                             bo + (size_t)l*128, g1 + (size_t)l*128,
                                             b1 + (size_t)l*128,
                                             W1T + (size_t)l*65536, bf1 + (size_t)l*512,
                                             W2T + (size_t)l*65536, bf2 + (size_t)l*128,
                                             g2 + (size_t)l*128, b2 + (size_t)l*128);
  }

  probs_head_kernel<<<256, 512, 0, stream>>>(Xb, VMEAS, VMEASB,
                                             fcW1, fcb1, fcW2, fcb2, out);
}